// Round 5
// baseline (384.931 us; speedup 1.0000x reference)
//
#include <hip/hip_runtime.h>

#define NUM_BINS 256
#define NPI (3*512*512)   // 786432 elements per image
#define TPB 256
#define MMX_BLOCKS 32     // minmax blocks per image
#define BZ_BLOCKS 32      // binize blocks per image
#define MM_BLOCKS 16      // histogram-accumulate blocks per image
#define GB_PER_IMG 32     // gather blocks per image
#define NSUB 32           // LDS sub-histograms per block (2 lanes/wave per sub)
#define SUBSTRIDE 257     // 257 % 32 == 1: base bank of sub s is s -> spread
#define G_VEC 8           // packed uints (4 bins each) per thread per iter in gather

typedef float f32x4 __attribute__((ext_vector_type(4)));

// Must bit-match the f32 reference: (v-mn)*255 / (mx-mn+1e-8), clip, trunc.
// Keep the real division — a reciprocal precompute shifts boundary bins.
__device__ __forceinline__ int bin_of(float v, float mn, float denom) {
  float norm = (v - mn) * 255.0f / denom;
  norm = fminf(fmaxf(norm, 0.0f), 255.0f);
  return (int)norm;
}

__device__ __forceinline__ unsigned pack4(int b0, int b1, int b2, int b3) {
  return (unsigned)b0 | ((unsigned)b1 << 8) | ((unsigned)b2 << 16) | ((unsigned)b3 << 24);
}

// ---- pass 1: per-block min/max (plain f32 slots, no atomics) ----
// 2048 blocks; explicit 6x4 loop guarantees 4 float4 loads in flight.
__global__ void minmax_k(const float4* __restrict__ x,
                         float* __restrict__ mmn, float* __restrict__ mmx) {
  const int chunk4 = NPI / 4 / MMX_BLOCKS;  // 6144 float4 per block
  int img = blockIdx.x / MMX_BLOCKS;
  int blk = blockIdx.x % MMX_BLOCKS;
  const float4* p = x + (size_t)img * (NPI/4) + (size_t)blk * chunk4;
  float mn = 3.4e38f, mx = -3.4e38f;
  #pragma unroll
  for (int it = 0; it < chunk4 / (TPB * 4); ++it) {  // 6 iterations
    int i0 = threadIdx.x + it * TPB * 4;
    float4 v0 = p[i0];
    float4 v1 = p[i0 + TPB];
    float4 v2 = p[i0 + 2*TPB];
    float4 v3 = p[i0 + 3*TPB];
    mn = fminf(mn, fminf(fminf(v0.x, v0.y), fminf(v0.z, v0.w)));
    mx = fmaxf(mx, fmaxf(fmaxf(v0.x, v0.y), fmaxf(v0.z, v0.w)));
    mn = fminf(mn, fminf(fminf(v1.x, v1.y), fminf(v1.z, v1.w)));
    mx = fmaxf(mx, fmaxf(fmaxf(v1.x, v1.y), fmaxf(v1.z, v1.w)));
    mn = fminf(mn, fminf(fminf(v2.x, v2.y), fminf(v2.z, v2.w)));
    mx = fmaxf(mx, fmaxf(fmaxf(v2.x, v2.y), fmaxf(v2.z, v2.w)));
    mn = fminf(mn, fminf(fminf(v3.x, v3.y), fminf(v3.z, v3.w)));
    mx = fmaxf(mx, fmaxf(fmaxf(v3.x, v3.y), fmaxf(v3.z, v3.w)));
  }
  for (int off = 32; off > 0; off >>= 1) {
    mn = fminf(mn, __shfl_down(mn, off));
    mx = fmaxf(mx, __shfl_down(mx, off));
  }
  __shared__ float smn[4], smx[4];
  int wave = threadIdx.x >> 6, lane = threadIdx.x & 63;
  if (lane == 0) { smn[wave] = mn; smx[wave] = mx; }
  __syncthreads();
  if (threadIdx.x == 0) {
    mmn[blockIdx.x] = fminf(fminf(smn[0], smn[1]), fminf(smn[2], smn[3]));
    mmx[blockIdx.x] = fmaxf(fmaxf(smx[0], smx[1]), fmaxf(smx[2], smx[3]));
  }
}

__device__ __forceinline__ void load_minmax(const float* __restrict__ mmn,
                                            const float* __restrict__ mmx,
                                            int img, float* s_mn, float* s_dn) {
  if (threadIdx.x < MMX_BLOCKS) {  // 32 lanes, one wave
    float a = mmn[img * MMX_BLOCKS + threadIdx.x];
    float b = mmx[img * MMX_BLOCKS + threadIdx.x];
    for (int off = MMX_BLOCKS / 2; off > 0; off >>= 1) {
      a = fminf(a, __shfl_down(a, off));
      b = fmaxf(b, __shfl_down(b, off));
    }
    if (threadIdx.x == 0) { *s_mn = a; *s_dn = b - a + 1e-8f; }
  }
}

// ---- pass 2a: binize — x (L3-warm) -> packed uint8 bins ----
// Pure streaming compute: no LDS histograms, no atomics -> full occupancy,
// division latency overlapped by 4 loads + 4 stores in flight.
__global__ void binize_k(const float4* __restrict__ x,
                         const float* __restrict__ mmn, const float* __restrict__ mmx,
                         unsigned* __restrict__ bins32) {
  __shared__ float s_mn, s_dn;
  load_minmax(mmn, mmx, blockIdx.x / BZ_BLOCKS, &s_mn, &s_dn);
  __syncthreads();
  float mn = s_mn, denom = s_dn;
  const int chunk4 = NPI / 4 / BZ_BLOCKS;  // 6144
  int img = blockIdx.x / BZ_BLOCKS;
  int blk = blockIdx.x % BZ_BLOCKS;
  size_t gbase = (size_t)img * (NPI/4) + (size_t)blk * chunk4;
  const float4* p = x + gbase;
  unsigned* q = bins32 + gbase;
  #pragma unroll
  for (int it = 0; it < chunk4 / (TPB * 4); ++it) {  // 6 iterations
    int i0 = threadIdx.x + it * TPB * 4;
    float4 v0 = p[i0];
    float4 v1 = p[i0 + TPB];
    float4 v2 = p[i0 + 2*TPB];
    float4 v3 = p[i0 + 3*TPB];
    q[i0]         = pack4(bin_of(v0.x, mn, denom), bin_of(v0.y, mn, denom),
                          bin_of(v0.z, mn, denom), bin_of(v0.w, mn, denom));
    q[i0 + TPB]   = pack4(bin_of(v1.x, mn, denom), bin_of(v1.y, mn, denom),
                          bin_of(v1.z, mn, denom), bin_of(v1.w, mn, denom));
    q[i0 + 2*TPB] = pack4(bin_of(v2.x, mn, denom), bin_of(v2.y, mn, denom),
                          bin_of(v2.z, mn, denom), bin_of(v2.w, mn, denom));
    q[i0 + 3*TPB] = pack4(bin_of(v3.x, mn, denom), bin_of(v3.y, mn, denom),
                          bin_of(v3.z, mn, denom), bin_of(v3.w, mn, denom));
  }
}

// ---- pass 2b: histogram from bins (L2/L3-hot, 4x less data than x) ----
// No division, no f32: load 8 packed words, 32 byte-extract LDS atomics.
__global__ void histb_k(const unsigned* __restrict__ bins32,
                        int* __restrict__ histblk) {
  __shared__ int sh[NSUB * SUBSTRIDE];
  for (int i = threadIdx.x; i < NSUB * SUBSTRIDE; i += TPB) sh[i] = 0;
  __syncthreads();
  const int wpb = NPI / 4 / MM_BLOCKS;  // 12288 words per block
  int img = blockIdx.x / MM_BLOCKS;
  int blk = blockIdx.x % MM_BLOCKS;
  const unsigned* p = bins32 + (size_t)img * (NPI/4) + (size_t)blk * wpb;
  int* mysub = sh + (threadIdx.x & (NSUB - 1)) * SUBSTRIDE;
  for (int it = 0; it < wpb / (TPB * 8); ++it) {  // 6 iterations
    unsigned w[8];
    #pragma unroll
    for (int k = 0; k < 8; ++k) w[k] = p[threadIdx.x + it * TPB * 8 + k * TPB];
    #pragma unroll
    for (int k = 0; k < 8; ++k) {
      atomicAdd(&mysub[w[k] & 255u], 1);
      atomicAdd(&mysub[(w[k] >> 8) & 255u], 1);
      atomicAdd(&mysub[(w[k] >> 16) & 255u], 1);
      atomicAdd(&mysub[w[k] >> 24], 1);
    }
  }
  __syncthreads();
  int bin = threadIdx.x;
  int s = 0;
  #pragma unroll
  for (int c = 0; c < NSUB; ++c) s += sh[c * SUBSTRIDE + bin];
  histblk[blockIdx.x * NUM_BINS + bin] = s;  // coalesced, no atomic
}

// ---- pass 3: gather with folded scan ----
// Each block recomputes the per-image cdf from the 16 partial histograms
// (16 KB L2-hot read + 256-wide scan, ~µs across the grid) — saves a dispatch.
__global__ void gather_bins_k(const unsigned* __restrict__ bins32,
                              const int* __restrict__ histblk,
                              float4* __restrict__ out) {
  __shared__ int s[NUM_BINS];
  __shared__ float c[NUM_BINS];
  const int f4pi = NPI / 4;                    // 196608
  const int chunk4 = f4pi / GB_PER_IMG;        // 6144
  const int ITERS = chunk4 / (TPB * G_VEC);    // 3
  int img = blockIdx.x / GB_PER_IMG;
  int blk = blockIdx.x % GB_PER_IMG;
  int t = threadIdx.x;
  int v = 0;
  #pragma unroll
  for (int b = 0; b < MM_BLOCKS; ++b)
    v += histblk[(img * MM_BLOCKS + b) * NUM_BINS + t];
  s[t] = v;
  __syncthreads();
  for (int off = 1; off < NUM_BINS; off <<= 1) {
    int add = (t >= off) ? s[t - off] : 0;
    __syncthreads();
    s[t] += add;
    __syncthreads();
  }
  {
    int cdf = s[t], c0 = s[0], cN = s[NUM_BINS - 1];
    // counts are exact integers < 2^24, so int math == the reference's f32 cumsum
    c[t] = (float)(cdf - c0) / ((float)(cN - c0) + 1e-8f);
  }
  __syncthreads();
  size_t base = (size_t)img * f4pi + (size_t)blk * chunk4 + threadIdx.x;
  for (int it = 0; it < ITERS; ++it) {
    size_t b0 = base + (size_t)it * TPB * G_VEC;
    unsigned bv[G_VEC];
    #pragma unroll
    for (int j = 0; j < G_VEC; ++j) bv[j] = bins32[b0 + (size_t)j * TPB];
    #pragma unroll
    for (int j = 0; j < G_VEC; ++j) {
      unsigned b = bv[j];
      f32x4 o;
      o.x = c[b & 255u];
      o.y = c[(b >> 8) & 255u];
      o.z = c[(b >> 16) & 255u];
      o.w = c[b >> 24];
      // nontemporal: out is a pure stream; keep bins32 resident in LLC
      __builtin_nontemporal_store(o, (f32x4*)&out[b0 + (size_t)j * TPB]);
    }
  }
}

// ---------------- fallback path (workspace too small for bin cache) ----------------
__global__ void hist_k(const float4* __restrict__ x,
                       const float* __restrict__ mmn, const float* __restrict__ mmx,
                       int* __restrict__ histblk) {
  __shared__ int sh[NSUB * SUBSTRIDE];
  __shared__ float s_mn, s_dn;
  load_minmax(mmn, mmx, blockIdx.x / MM_BLOCKS, &s_mn, &s_dn);
  for (int i = threadIdx.x; i < NSUB * SUBSTRIDE; i += TPB) sh[i] = 0;
  const int chunk4 = NPI / 4 / MM_BLOCKS;  // 12288
  int img = blockIdx.x / MM_BLOCKS;
  int blk = blockIdx.x % MM_BLOCKS;
  __syncthreads();
  float mn = s_mn, denom = s_dn;
  const float4* p = x + (size_t)img * (NPI/4) + (size_t)blk * chunk4;
  int* mysub = sh + (threadIdx.x & (NSUB - 1)) * SUBSTRIDE;
  for (int i = threadIdx.x; i < chunk4; i += TPB * 4) {
    float4 v0 = p[i];
    float4 v1 = p[i + TPB];
    float4 v2 = p[i + 2*TPB];
    float4 v3 = p[i + 3*TPB];
    atomicAdd(&mysub[bin_of(v0.x, mn, denom)], 1);
    atomicAdd(&mysub[bin_of(v0.y, mn, denom)], 1);
    atomicAdd(&mysub[bin_of(v0.z, mn, denom)], 1);
    atomicAdd(&mysub[bin_of(v0.w, mn, denom)], 1);
    atomicAdd(&mysub[bin_of(v1.x, mn, denom)], 1);
    atomicAdd(&mysub[bin_of(v1.y, mn, denom)], 1);
    atomicAdd(&mysub[bin_of(v1.z, mn, denom)], 1);
    atomicAdd(&mysub[bin_of(v1.w, mn, denom)], 1);
    atomicAdd(&mysub[bin_of(v2.x, mn, denom)], 1);
    atomicAdd(&mysub[bin_of(v2.y, mn, denom)], 1);
    atomicAdd(&mysub[bin_of(v2.z, mn, denom)], 1);
    atomicAdd(&mysub[bin_of(v2.w, mn, denom)], 1);
    atomicAdd(&mysub[bin_of(v3.x, mn, denom)], 1);
    atomicAdd(&mysub[bin_of(v3.y, mn, denom)], 1);
    atomicAdd(&mysub[bin_of(v3.z, mn, denom)], 1);
    atomicAdd(&mysub[bin_of(v3.w, mn, denom)], 1);
  }
  __syncthreads();
  int bin = threadIdx.x;
  int s = 0;
  #pragma unroll
  for (int c = 0; c < NSUB; ++c) s += sh[c * SUBSTRIDE + bin];
  histblk[blockIdx.x * NUM_BINS + bin] = s;
}

__global__ void scan_k(const int* __restrict__ histblk, float* __restrict__ cdfn) {
  __shared__ int s[NUM_BINS];
  int img = blockIdx.x, t = threadIdx.x;
  int v = 0;
  #pragma unroll
  for (int b = 0; b < MM_BLOCKS; ++b)
    v += histblk[(img * MM_BLOCKS + b) * NUM_BINS + t];
  s[t] = v;
  __syncthreads();
  for (int off = 1; off < NUM_BINS; off <<= 1) {
    int add = (t >= off) ? s[t - off] : 0;
    __syncthreads();
    s[t] += add;
    __syncthreads();
  }
  int cdf = s[t], c0 = s[0], cN = s[NUM_BINS - 1];
  cdfn[img * NUM_BINS + t] = (float)(cdf - c0) / ((float)(cN - c0) + 1e-8f);
}

__global__ void gather_x_k(const float4* __restrict__ x,
                           const float* __restrict__ mmn, const float* __restrict__ mmx,
                           const float* __restrict__ cdfn,
                           float4* __restrict__ out) {
  __shared__ float c[NUM_BINS];
  __shared__ float s_mn, s_dn;
  const int f4pi = NPI / 4;
  const int CHUNK = TPB * 4;
  const int bpi = f4pi / CHUNK;  // 192
  int img = blockIdx.x / bpi;
  int blk = blockIdx.x % bpi;
  c[threadIdx.x] = cdfn[img * NUM_BINS + threadIdx.x];
  load_minmax(mmn, mmx, img, &s_mn, &s_dn);
  __syncthreads();
  float mn = s_mn, denom = s_dn;
  size_t base = (size_t)img * f4pi + (size_t)blk * CHUNK + threadIdx.x;
  #pragma unroll
  for (int j = 0; j < 4; ++j) {
    float4 v = x[base + (size_t)j * TPB];
    f32x4 o;
    o.x = c[bin_of(v.x, mn, denom)];
    o.y = c[bin_of(v.y, mn, denom)];
    o.z = c[bin_of(v.z, mn, denom)];
    o.w = c[bin_of(v.w, mn, denom)];
    __builtin_nontemporal_store(o, (f32x4*)&out[base + (size_t)j * TPB]);
  }
}

extern "C" void kernel_launch(void* const* d_in, const int* in_sizes, int n_in,
                              void* d_out, int out_size, void* d_ws, size_t ws_size,
                              hipStream_t stream) {
  const float* x = (const float*)d_in[0];
  float* out = (float*)d_out;
  int B = in_sizes[0] / NPI;  // 64 images

  // workspace layout:
  //   mmn:    B*32 f32        (per-block mins)
  //   mmx:    B*32 f32        (per-block maxs)
  //   histblk B*16*256 i32    (per-block histograms)
  //   cdfn:   B*256 f32       (fallback only)
  //   bins:   B*NPI u8        (packed bin cache, optional)
  char* ws = (char*)d_ws;
  float* mmn = (float*)ws;
  float* mmx = mmn + (size_t)B * MMX_BLOCKS;
  int* histblk = (int*)(mmx + (size_t)B * MMX_BLOCKS);
  float* cdfn = (float*)(histblk + (size_t)B * MM_BLOCKS * NUM_BINS);
  unsigned* bins32 = (unsigned*)(cdfn + (size_t)B * NUM_BINS);
  size_t need = (size_t)((char*)bins32 - ws) + (size_t)B * NPI;
  bool use_bins = (ws_size >= need);

  minmax_k<<<B * MMX_BLOCKS, TPB, 0, stream>>>((const float4*)x, mmn, mmx);
  if (use_bins) {
    binize_k<<<B * BZ_BLOCKS, TPB, 0, stream>>>((const float4*)x, mmn, mmx, bins32);
    histb_k<<<B * MM_BLOCKS, TPB, 0, stream>>>(bins32, histblk);
    gather_bins_k<<<B * GB_PER_IMG, TPB, 0, stream>>>(bins32, histblk, (float4*)out);
  } else {
    hist_k<<<B * MM_BLOCKS, TPB, 0, stream>>>((const float4*)x, mmn, mmx, histblk);
    scan_k<<<B, NUM_BINS, 0, stream>>>(histblk, cdfn);
    gather_x_k<<<B * (NPI/4/(TPB*4)), TPB, 0, stream>>>((const float4*)x, mmn, mmx, cdfn,
                                                        (float4*)out);
  }
}